// Round 2
// baseline (80.416 us; speedup 1.0000x reference)
//
#include <hip/hip_runtime.h>

#define N_FLT 48
#define N_KNOTS 91

// Spline interpolation: out[i] = lerp over yk knots, per-channel (i % 48).
// Memory-bound elementwise op; yk (17.5 KB) staged in LDS for the gather.
__global__ __launch_bounds__(256) void spline_interp_kernel(
    const float* __restrict__ x,
    const float* __restrict__ yk,
    float* __restrict__ out,
    int n4)
{
    __shared__ float yk_s[N_KNOTS * N_FLT];
    for (int i = threadIdx.x; i < N_KNOTS * N_FLT; i += 256)
        yk_s[i] = yk[i];
    __syncthreads();

    // reference: clip(xS, 1e-5, N_KNOTS - 1.00001) = [1e-5, 89.99999]
    const float upper = (float)N_KNOTS - 1.00001f;  // 89.99999f  (round-1 fix: was 88.99999)

    int idx4 = blockIdx.x * 256 + threadIdx.x;
    const int stride = gridDim.x * 256;

    for (; idx4 < n4; idx4 += stride) {
        float4 xv = reinterpret_cast<const float4*>(x)[idx4];
        // channel of first element of this float4; 48 % 4 == 0 so no wrap
        const int c0 = (idx4 * 4) % N_FLT;

        float xin[4] = {xv.x, xv.y, xv.z, xv.w};
        float r[4];
#pragma unroll
        for (int j = 0; j < 4; ++j) {
            // xS = (x - (-3)) / (6/90)  ->  (x + 3) * 15
            float xS = (xin[j] + 3.0f) * 15.0f;
            xS = fminf(fmaxf(xS, 1e-5f), upper);
            float xF = floorf(xS);
            float k  = xS - xF;
            int  idx = (int)xF;
            idx = min(max(idx, 0), N_KNOTS - 2);
            float yf = yk_s[idx * N_FLT + c0 + j];
            float yc = yk_s[(idx + 1) * N_FLT + c0 + j];
            r[j] = yf * (1.0f - k) + k * yc;
        }
        float4 ov = make_float4(r[0], r[1], r[2], r[3]);
        reinterpret_cast<float4*>(out)[idx4] = ov;
    }
}

extern "C" void kernel_launch(void* const* d_in, const int* in_sizes, int n_in,
                              void* d_out, int out_size, void* d_ws, size_t ws_size,
                              hipStream_t stream) {
    const float* x  = (const float*)d_in[0];
    const float* yk = (const float*)d_in[1];
    float* out = (float*)d_out;

    int n  = in_sizes[0];      // 16*256*256*48 = 50,331,648 (divisible by 4)
    int n4 = n / 4;

    const int block = 256;
    const int grid  = 2048;    // 256 CUs * 8 blocks, grid-stride covers the rest

    spline_interp_kernel<<<grid, block, 0, stream>>>(x, yk, out, n4);
}

// Round 4
// 76.799 us; speedup vs baseline: 1.0471x; 1.0471x over previous
//
#include <hip/hip_runtime.h>

#define N_FLT 48
#define N_KNOTS 91

typedef float f32x4 __attribute__((ext_vector_type(4)));  // native vec for nontemporal builtins

// Spline interpolation: out[i] = lerp over yk knots, per-channel (i % 48).
// Memory-bound elementwise op; yk (17.5 KB) staged in LDS for the gather.
// R2: nontemporal load/store, 2x float4 unroll for MLP, drop redundant clamp.
// R3: ext_vector_type for nontemporal builtins (HIP float4 class rejected).
__global__ __launch_bounds__(256) void spline_interp_kernel(
    const float* __restrict__ x,
    const float* __restrict__ yk,
    float* __restrict__ out,
    int n4)
{
    __shared__ float yk_s[N_KNOTS * N_FLT];
    for (int i = threadIdx.x; i < N_KNOTS * N_FLT; i += 256)
        yk_s[i] = yk[i];
    __syncthreads();

    // reference: clip(xS, 1e-5, N_KNOTS - 1.00001) = [1e-5, 89.99999]
    const float upper = (float)N_KNOTS - 1.00001f;  // 89.99999f

    const int tid    = blockIdx.x * 256 + threadIdx.x;
    const int stride = gridDim.x * 256;

    const f32x4* xv4  = reinterpret_cast<const f32x4*>(x);
    f32x4*       out4 = reinterpret_cast<f32x4*>(out);

    // main loop: 2 float4 per thread per iteration, second offset by `stride`
    int idx4 = tid;
    for (; idx4 + stride < n4; idx4 += 2 * stride) {
        const int idxB = idx4 + stride;
        f32x4 xa = __builtin_nontemporal_load(xv4 + idx4);
        f32x4 xb = __builtin_nontemporal_load(xv4 + idxB);
        const int cA = (idx4 * 4) % N_FLT;   // 48%4==0 -> no wrap within float4
        const int cB = (idxB * 4) % N_FLT;

        f32x4 rA, rB;
#pragma unroll
        for (int j = 0; j < 4; ++j) {
            float xS = (xa[j] + 3.0f) * 15.0f;             // (x+3)/(6/90)
            xS = fminf(fmaxf(xS, 1e-5f), upper);
            float xF = floorf(xS);
            float k  = xS - xF;
            int  idx = (int)xF;                            // in [0, 89] by clamp
            float yf = yk_s[idx * N_FLT + cA + j];
            float yc = yk_s[(idx + 1) * N_FLT + cA + j];
            rA[j] = yf * (1.0f - k) + k * yc;
        }
#pragma unroll
        for (int j = 0; j < 4; ++j) {
            float xS = (xb[j] + 3.0f) * 15.0f;
            xS = fminf(fmaxf(xS, 1e-5f), upper);
            float xF = floorf(xS);
            float k  = xS - xF;
            int  idx = (int)xF;
            float yf = yk_s[idx * N_FLT + cB + j];
            float yc = yk_s[(idx + 1) * N_FLT + cB + j];
            rB[j] = yf * (1.0f - k) + k * yc;
        }
        __builtin_nontemporal_store(rA, out4 + idx4);
        __builtin_nontemporal_store(rB, out4 + idxB);
    }
    // tail: remaining single float4s
    for (; idx4 < n4; idx4 += stride) {
        f32x4 xv = __builtin_nontemporal_load(xv4 + idx4);
        const int c0 = (idx4 * 4) % N_FLT;
        f32x4 r;
#pragma unroll
        for (int j = 0; j < 4; ++j) {
            float xS = (xv[j] + 3.0f) * 15.0f;
            xS = fminf(fmaxf(xS, 1e-5f), upper);
            float xF = floorf(xS);
            float k  = xS - xF;
            int  idx = (int)xF;
            float yf = yk_s[idx * N_FLT + c0 + j];
            float yc = yk_s[(idx + 1) * N_FLT + c0 + j];
            r[j] = yf * (1.0f - k) + k * yc;
        }
        __builtin_nontemporal_store(r, out4 + idx4);
    }
}

extern "C" void kernel_launch(void* const* d_in, const int* in_sizes, int n_in,
                              void* d_out, int out_size, void* d_ws, size_t ws_size,
                              hipStream_t stream) {
    const float* x  = (const float*)d_in[0];
    const float* yk = (const float*)d_in[1];
    float* out = (float*)d_out;

    int n  = in_sizes[0];      // 16*256*256*48 = 50,331,648 (divisible by 4)
    int n4 = n / 4;

    const int block = 256;
    const int grid  = 2048;    // 256 CUs * 8 blocks, grid-stride covers the rest

    spline_interp_kernel<<<grid, block, 0, stream>>>(x, yk, out, n4);
}